// Round 2
// baseline (1550.399 us; speedup 1.0000x reference)
//
#include <hip/hip_runtime.h>
#include <hip/hip_bf16.h>

typedef unsigned short u16;
typedef unsigned int   u32;

#define NN 320
#define NP (NN*NN)
#define DD 128
#define NH 4
#define DHH 32
#define QSCALE 0.17677669529663687f

__device__ __forceinline__ float b2f(u16 u){
    union { u32 i; float f; } v; v.i = ((u32)u) << 16; return v.f;
}
__device__ __forceinline__ u16 f2b(float f){
    union { float f; u32 i; } v; v.f = f;
    u32 x = v.i;
    u32 r = x + 0x7fffu + ((x >> 16) & 1u);
    return (u16)(r >> 16);
}

// ---------------- LayerNorm + edge-bias kernel ----------------
// One wave (64 lanes) per position p; lane handles 2 of the 128 dims.
// bias[h][p] = sum_d x_raw[p][d] * wb[h][d]  (un-normalized input!)
__global__ __launch_bounds__(256) void k_ln_bias(
    const float* __restrict__ xin, const float* __restrict__ ng, const float* __restrict__ nb,
    const float* __restrict__ wb, u16* __restrict__ xn, float* __restrict__ bias)
{
    const int w = threadIdx.x >> 6, lane = threadIdx.x & 63;
    const int p = blockIdx.x * 4 + w;
    const int d0 = lane * 2;
    const float2 xp = *(const float2*)(xin + (size_t)p*DD + d0);
    const float x0 = xp.x, x1 = xp.y;
    float s = x0 + x1;
    #pragma unroll
    for (int m = 1; m < 64; m <<= 1) s += __shfl_xor(s, m);
    const float mu = s * (1.f/128.f);
    const float dx0 = x0 - mu, dx1 = x1 - mu;
    float vv = dx0*dx0 + dx1*dx1;
    #pragma unroll
    for (int m = 1; m < 64; m <<= 1) vv += __shfl_xor(vv, m);
    const float rstd = rsqrtf(vv * (1.f/128.f) + 1e-5f);
    const float2 gp = *(const float2*)(ng + d0);
    const float2 bp = *(const float2*)(nb + d0);
    const float y0 = dx0*rstd*gp.x + bp.x;
    const float y1 = dx1*rstd*gp.y + bp.y;
    const u32 ow = (u32)f2b(y0) | ((u32)f2b(y1) << 16);
    *(u32*)(xn + (size_t)p*DD + d0) = ow;
    #pragma unroll
    for (int h = 0; h < NH; ++h){
        const float2 wp = *(const float2*)(wb + h*DD + d0);
        float bb = x0*wp.x + x1*wp.y;
        #pragma unroll
        for (int m = 1; m < 64; m <<= 1) bb += __shfl_xor(bb, m);
        if (lane == 0) bias[(size_t)h*NP + p] = bb;
    }
}

// ---------------- Tiled GEMM: A[M x 128](bf16) @ W[128 outs x 128](f32)^T ----------------
// Block: 256 threads -> 128 pos x 128 outs. Thread: 8x8 accum.
// MODE 0: plain->bf16  1: *QSCALE->bf16 (q)  2: sigmoid(v+bg)->bf16 (gates)
// MODE 3: +bo +residual -> f32 out
template<int MODE>
__global__ __launch_bounds__(256) void k_gemm(
    const u16* __restrict__ Amat, const float* __restrict__ Wmat, void* __restrict__ Outp,
    const float* __restrict__ bgv, const float* __restrict__ bov, const float* __restrict__ xres)
{
    __shared__ float As[32][136];   // [k][pos]
    __shared__ float Bs[32][136];   // [k][e]
    const int tid = threadIdx.x;
    const int tx = tid & 15, ty = tid >> 4;
    const int pbase = blockIdx.x * 128;
    float acc[8][8] = {};

    for (int kt = 0; kt < 4; ++kt){
        #pragma unroll
        for (int rr = 0; rr < 2; ++rr){
            const int s = tid + rr*256;
            const int row = s >> 2, seg = s & 3;
            uint4 a4 = *(const uint4*)(Amat + (size_t)(pbase+row)*DD + kt*32 + seg*8);
            union { uint4 q; u16 us[8]; } ua; ua.q = a4;
            #pragma unroll
            for (int u = 0; u < 8; ++u) As[seg*8+u][row] = b2f(ua.us[u]);
            const float4 w4a = *(const float4*)(Wmat + (size_t)row*DD + kt*32 + seg*8);
            const float4 w4b = *(const float4*)(Wmat + (size_t)row*DD + kt*32 + seg*8 + 4);
            Bs[seg*8+0][row] = w4a.x; Bs[seg*8+1][row] = w4a.y;
            Bs[seg*8+2][row] = w4a.z; Bs[seg*8+3][row] = w4a.w;
            Bs[seg*8+4][row] = w4b.x; Bs[seg*8+5][row] = w4b.y;
            Bs[seg*8+6][row] = w4b.z; Bs[seg*8+7][row] = w4b.w;
        }
        __syncthreads();
        #pragma unroll
        for (int k = 0; k < 32; ++k){
            const float4 a0 = *(const float4*)&As[k][ty*8];
            const float4 a1 = *(const float4*)&As[k][ty*8+4];
            const float4 b0 = *(const float4*)&Bs[k][tx*8];
            const float4 b1 = *(const float4*)&Bs[k][tx*8+4];
            const float av[8] = {a0.x,a0.y,a0.z,a0.w,a1.x,a1.y,a1.z,a1.w};
            const float bv[8] = {b0.x,b0.y,b0.z,b0.w,b1.x,b1.y,b1.z,b1.w};
            #pragma unroll
            for (int i = 0; i < 8; ++i)
                #pragma unroll
                for (int j = 0; j < 8; ++j)
                    acc[i][j] = fmaf(av[i], bv[j], acc[i][j]);
        }
        __syncthreads();
    }

    const int e0 = tx * 8;
    #pragma unroll
    for (int i = 0; i < 8; ++i){
        const size_t pos = (size_t)pbase + ty*8 + i;
        float v[8];
        #pragma unroll
        for (int j = 0; j < 8; ++j) v[j] = acc[i][j];
        if (MODE == 1){
            #pragma unroll
            for (int j = 0; j < 8; ++j) v[j] *= QSCALE;
        } else if (MODE == 2){
            #pragma unroll
            for (int j = 0; j < 8; ++j) v[j] = 1.f/(1.f + __expf(-(v[j] + bgv[e0+j])));
        }
        if (MODE == 3){
            const float4 xr0 = *(const float4*)(xres + pos*DD + e0);
            const float4 xr1 = *(const float4*)(xres + pos*DD + e0 + 4);
            const float xr[8] = {xr0.x,xr0.y,xr0.z,xr0.w,xr1.x,xr1.y,xr1.z,xr1.w};
            float* Of = (float*)Outp;
            float4 o0, o1;
            o0.x = v[0] + bov[e0+0] + xr[0]; o0.y = v[1] + bov[e0+1] + xr[1];
            o0.z = v[2] + bov[e0+2] + xr[2]; o0.w = v[3] + bov[e0+3] + xr[3];
            o1.x = v[4] + bov[e0+4] + xr[4]; o1.y = v[5] + bov[e0+5] + xr[5];
            o1.z = v[6] + bov[e0+6] + xr[6]; o1.w = v[7] + bov[e0+7] + xr[7];
            *(float4*)(Of + pos*DD + e0)     = o0;
            *(float4*)(Of + pos*DD + e0 + 4) = o1;
        } else {
            u16* Ob = (u16*)Outp;
            union { uint4 q; u16 us[8]; } o;
            #pragma unroll
            for (int j = 0; j < 8; ++j) o.us[j] = f2b(v[j]);
            *(uint4*)(Ob + pos*DD + e0) = o.q;
        }
    }
}

// ---------------- Attention kernel: one block per (h, r) ----------------
// ROWPASS=1: attend along columns of row r; ROWPASS=0: along rows of column r.
template<int ROWPASS>
__global__ __launch_bounds__(256) void k_attn(
    const u16* __restrict__ Pq, const u16* __restrict__ Pk, const u16* __restrict__ Pv,
    const u16* __restrict__ Pg, const float* __restrict__ bias, u16* __restrict__ Aout)
{
    __shared__ u16 ks[NN][34];        // padded: 17-word row stride -> conflict-free
    __shared__ u16 vsB[40][32][8];    // [j/8][e][j%8] blocked for dense b128 reads
    __shared__ u16 qs[NN][32];
    __shared__ float pw[8][NN];       // 2 rows per wave (2-query blocking)
    const int h = blockIdx.x, r = blockIdx.y;
    const int tid = threadIdx.x;

    for (int s = tid; s < NN*4; s += 256){
        const int idx = s >> 2, seg = s & 3;
        const size_t base = (size_t)(ROWPASS ? (r*NN + idx) : (idx*NN + r)) * DD + h*DHH + seg*8;
        const uint4 q4 = *(const uint4*)(Pq + base);
        const uint4 k4 = *(const uint4*)(Pk + base);
        const uint4 v4 = *(const uint4*)(Pv + base);
        *(uint4*)&qs[idx][seg*8] = q4;
        u32* kd = (u32*)&ks[idx][seg*8];
        kd[0]=k4.x; kd[1]=k4.y; kd[2]=k4.z; kd[3]=k4.w;
        union { uint4 q; u16 us[8]; } vu; vu.q = v4;
        const int jb = idx >> 3, jo = idx & 7;
        #pragma unroll
        for (int u = 0; u < 8; ++u) vsB[jb][seg*8+u][jo] = vu.us[u];
    }
    __syncthreads();

    const int w = tid >> 6, lane = tid & 63;
    const int e = lane & 31, jh = lane >> 5;
    float* pw0 = pw[w*2];
    float* pw1 = pw[w*2+1];

    for (int g = w; g < 160; g += 4){
        const int i0 = g * 2;
        // preload 2 query rows into f32 registers
        float q0[32], q1[32];
        #pragma unroll
        for (int t = 0; t < 16; ++t){
            const u32 a = *(const u32*)&qs[i0][t*2];
            q0[t*2] = b2f((u16)a); q0[t*2+1] = b2f((u16)(a>>16));
            const u32 b = *(const u32*)&qs[i0+1][t*2];
            q1[t*2] = b2f((u16)b); q1[t*2+1] = b2f((u16)(b>>16));
        }
        float da[5], db[5];
        #pragma unroll
        for (int jc = 0; jc < 5; ++jc){
            const int j = jc*64 + lane;
            float a0 = 0.f, a1 = 0.f;
            #pragma unroll
            for (int t = 0; t < 16; ++t){
                const u32 kp = *(const u32*)&ks[j][t*2];
                const float k0 = b2f((u16)kp), k1 = b2f((u16)(kp>>16));
                a0 = fmaf(q0[t*2],   k0, a0);
                a0 = fmaf(q0[t*2+1], k1, a0);
                a1 = fmaf(q1[t*2],   k0, a1);
                a1 = fmaf(q1[t*2+1], k1, a1);
            }
            const size_t bb = (size_t)h*NP + (size_t)i0*NN + j;
            da[jc] = a0 + bias[bb];
            db[jc] = a1 + bias[bb + NN];
        }
        // wave-wide softmax (all 320 j are valid: 5*64)
        float m0 = fmaxf(fmaxf(fmaxf(da[0],da[1]),fmaxf(da[2],da[3])),da[4]);
        float m1 = fmaxf(fmaxf(fmaxf(db[0],db[1]),fmaxf(db[2],db[3])),db[4]);
        #pragma unroll
        for (int msk = 1; msk < 64; msk <<= 1){
            m0 = fmaxf(m0, __shfl_xor(m0, msk));
            m1 = fmaxf(m1, __shfl_xor(m1, msk));
        }
        float s0 = 0.f, s1 = 0.f;
        #pragma unroll
        for (int jc = 0; jc < 5; ++jc){
            const float p0 = __expf(da[jc]-m0); s0 += p0; pw0[jc*64+lane] = p0;
            const float p1 = __expf(db[jc]-m1); s1 += p1; pw1[jc*64+lane] = p1;
        }
        #pragma unroll
        for (int msk = 1; msk < 64; msk <<= 1){
            s0 += __shfl_xor(s0, msk);
            s1 += __shfl_xor(s1, msk);
        }
        const float inv0 = 1.f/s0, inv1 = 1.f/s1;
        asm volatile("s_waitcnt lgkmcnt(0)" ::: "memory");
        __builtin_amdgcn_wave_barrier();
        // PV: lane = (e, j-half)
        float o0 = 0.f, o1 = 0.f;
        for (int jb = jh*20; jb < jh*20 + 20; ++jb){
            union { uint4 q; u16 us[8]; } vr;
            vr.q = *(const uint4*)&vsB[jb][e][0];
            const float4 pa0 = *(const float4*)&pw0[jb*8];
            const float4 pa1 = *(const float4*)&pw0[jb*8+4];
            const float4 pb0 = *(const float4*)&pw1[jb*8];
            const float4 pb1 = *(const float4*)&pw1[jb*8+4];
            const float pa[8] = {pa0.x,pa0.y,pa0.z,pa0.w,pa1.x,pa1.y,pa1.z,pa1.w};
            const float pb[8] = {pb0.x,pb0.y,pb0.z,pb0.w,pb1.x,pb1.y,pb1.z,pb1.w};
            float vv[8];
            #pragma unroll
            for (int u = 0; u < 8; ++u) vv[u] = b2f(vr.us[u]);
            #pragma unroll
            for (int u = 0; u < 8; ++u){
                o0 = fmaf(pa[u], vv[u], o0);
                o1 = fmaf(pb[u], vv[u], o1);
            }
        }
        o0 += __shfl_xor(o0, 32);
        o1 += __shfl_xor(o1, 32);
        if (jh == 0){
            const size_t posA0 = ROWPASS ? ((size_t)r*NN + i0) : ((size_t)i0*NN + r);
            const size_t posA1 = ROWPASS ? posA0 + 1 : posA0 + NN;
            const size_t off0 = posA0*DD + h*DHH + e;
            const size_t off1 = posA1*DD + h*DHH + e;
            Aout[off0] = f2b(o0 * inv0 * b2f(Pg[off0]));
            Aout[off1] = f2b(o1 * inv1 * b2f(Pg[off1]));
        }
    }
}

// ---------------- host-side launch ----------------
extern "C" void kernel_launch(void* const* d_in, const int* in_sizes, int n_in,
                              void* d_out, int out_size, void* d_ws, size_t ws_size,
                              hipStream_t stream)
{
    const float* x = (const float*)d_in[0];
    float* out = (float*)d_out;
    char* ws = (char*)d_ws;

    u16*   xn   = (u16*)ws;                                   // NP*DD bf16 (aliased as attn out)
    float* bias = (float*)(ws + (size_t)NP*DD*2);             // NH*NP f32
    u16*   Pq   = (u16*)(ws + (size_t)NP*DD*2 + (size_t)NH*NP*4);
    u16*   Pk   = Pq + (size_t)NP*DD;
    u16*   Pv   = Pk + (size_t)NP*DD;
    u16*   Pg   = Pv + (size_t)NP*DD;
    u16*   Aatt = xn;   // xn is dead after the projection GEMMs

    for (int pass = 0; pass < 2; ++pass){
        void* const* W = d_in + 1 + pass*9;
        const float* ng = (const float*)W[0];
        const float* nb = (const float*)W[1];
        const float* wb = (const float*)W[2];
        const float* wq = (const float*)W[3];
        const float* wkv= (const float*)W[4];
        const float* wg = (const float*)W[5];
        const float* bg = (const float*)W[6];
        const float* wo = (const float*)W[7];
        const float* bo = (const float*)W[8];
        const float* xin = (pass == 0) ? x : out;

        k_ln_bias<<<NP/4, 256, 0, stream>>>(xin, ng, nb, wb, xn, bias);
        k_gemm<1><<<NP/128, 256, 0, stream>>>(xn, wq,          (void*)Pq, nullptr, nullptr, nullptr);
        k_gemm<0><<<NP/128, 256, 0, stream>>>(xn, wkv,         (void*)Pk, nullptr, nullptr, nullptr);
        k_gemm<0><<<NP/128, 256, 0, stream>>>(xn, wkv + DD*DD, (void*)Pv, nullptr, nullptr, nullptr);
        k_gemm<2><<<NP/128, 256, 0, stream>>>(xn, wg,          (void*)Pg, bg, nullptr, nullptr);
        if (pass == 0) k_attn<1><<<dim3(NH, NN), 256, 0, stream>>>(Pq, Pk, Pv, Pg, bias, Aatt);
        else           k_attn<0><<<dim3(NH, NN), 256, 0, stream>>>(Pq, Pk, Pv, Pg, bias, Aatt);
        k_gemm<3><<<NP/128, 256, 0, stream>>>(Aatt, wo, (void*)out, nullptr, bo, xin);
    }
}

// Round 3
// 444.567 us; speedup vs baseline: 3.4874x; 3.4874x over previous
//
#include <hip/hip_runtime.h>
#include <hip/hip_bf16.h>

typedef unsigned short u16;
typedef unsigned int   u32;
typedef __attribute__((ext_vector_type(8))) short short8;
typedef __attribute__((ext_vector_type(4))) float f32x4;

#define NN 320
#define NP (NN*NN)
#define DD 128
#define NH 4
#define DHH 32
#define QSCALE 0.17677669529663687f

#define MFMA16(A,B,C) __builtin_amdgcn_mfma_f32_16x16x32_bf16(A,B,C,0,0,0)

__device__ __forceinline__ float b2f(u16 u){
    union { u32 i; float f; } v; v.i = ((u32)u) << 16; return v.f;
}
__device__ __forceinline__ u16 f2b(float f){
    union { float f; u32 i; } v; v.f = f;
    u32 x = v.i;
    u32 r = x + 0x7fffu + ((x >> 16) & 1u);
    return (u16)(r >> 16);
}
__device__ __forceinline__ u32 cvtpk(float lo, float hi){
    u32 r; asm("v_cvt_pk_bf16_f32 %0, %1, %2" : "=v"(r) : "v"(lo), "v"(hi)); return r;
}

// ---------------- LayerNorm + edge-bias kernel ----------------
// One wave per position p. Writes xn (bf16 normalized) and TRANSPOSED bias:
// bias_t[h][j][i] = x[i][j] . wb[h]   (i = x-row, j = x-col)
__global__ __launch_bounds__(256) void k_ln_bias(
    const float* __restrict__ xin, const float* __restrict__ ng, const float* __restrict__ nb,
    const float* __restrict__ wb, u16* __restrict__ xn, float* __restrict__ biasT)
{
    const int w = threadIdx.x >> 6, lane = threadIdx.x & 63;
    const int p = blockIdx.x * 4 + w;
    const int d0 = lane * 2;
    const float2 xp = *(const float2*)(xin + (size_t)p*DD + d0);
    const float x0 = xp.x, x1 = xp.y;
    float s = x0 + x1;
    #pragma unroll
    for (int m = 1; m < 64; m <<= 1) s += __shfl_xor(s, m);
    const float mu = s * (1.f/128.f);
    const float dx0 = x0 - mu, dx1 = x1 - mu;
    float vv = dx0*dx0 + dx1*dx1;
    #pragma unroll
    for (int m = 1; m < 64; m <<= 1) vv += __shfl_xor(vv, m);
    const float rstd = rsqrtf(vv * (1.f/128.f) + 1e-5f);
    const float2 gp = *(const float2*)(ng + d0);
    const float2 bp = *(const float2*)(nb + d0);
    const float y0 = dx0*rstd*gp.x + bp.x;
    const float y1 = dx1*rstd*gp.y + bp.y;
    const u32 ow = (u32)f2b(y0) | ((u32)f2b(y1) << 16);
    *(u32*)(xn + (size_t)p*DD + d0) = ow;
    const int pi = p / NN, pj = p - pi*NN;
    #pragma unroll
    for (int h = 0; h < NH; ++h){
        const float2 wp = *(const float2*)(wb + h*DD + d0);
        float bb = x0*wp.x + x1*wp.y;
        #pragma unroll
        for (int m = 1; m < 64; m <<= 1) bb += __shfl_xor(bb, m);
        if (lane == 0) biasT[(size_t)h*NP + (size_t)pj*NN + pi] = bb;
    }
}

// ---------------- MFMA GEMM: out[p][e] = sum_k A[p][k] * W[e][k] ----------------
// Block 256 thr = 4 waves (2x2 of 64x64). Tile 128 pos x 128 outs, K=128 staged.
// MODE 0: ->bf16  1: *QSCALE->bf16  2: sigmoid(+bg)->bf16  3: +bo+res->f32
template<int MODE>
__global__ __launch_bounds__(256) void k_gemm_mfma(
    const u16* __restrict__ Amat, const float* __restrict__ Wmat, void* __restrict__ Outp,
    const float* __restrict__ bgv, const float* __restrict__ bov, const float* __restrict__ xres)
{
    __shared__ u16 As[128*128];   // [row][k], 16B-slot swizzle: slot ^= row&7
    __shared__ u16 Ws[128*128];
    const int tid = threadIdx.x;
    const int pbase = blockIdx.x * 128;

    #pragma unroll
    for (int c = 0; c < 8; ++c){
        const int flat = tid + c*256;
        const int row = flat >> 4, s = flat & 15;
        const uint4 a4 = *(const uint4*)(Amat + (size_t)(pbase+row)*DD + s*8);
        *(uint4*)&As[row*128 + ((s ^ (row & 7)) << 3)] = a4;
        const float4 wa = *(const float4*)(Wmat + (size_t)row*DD + s*8);
        const float4 wbv = *(const float4*)(Wmat + (size_t)row*DD + s*8 + 4);
        union { uint4 q; u16 us[8]; } ww;
        ww.us[0]=f2b(wa.x);  ww.us[1]=f2b(wa.y);  ww.us[2]=f2b(wa.z);  ww.us[3]=f2b(wa.w);
        ww.us[4]=f2b(wbv.x); ww.us[5]=f2b(wbv.y); ww.us[6]=f2b(wbv.z); ww.us[7]=f2b(wbv.w);
        *(uint4*)&Ws[row*128 + ((s ^ (row & 7)) << 3)] = ww.q;
    }
    __syncthreads();

    const int w = tid >> 6, l = tid & 63;
    const int li = l & 15, g = l >> 4;
    const int wr = w >> 1, wc = w & 1;
    f32x4 acc[4][4] = {};

    #pragma unroll
    for (int ks = 0; ks < 4; ++ks){
        const int slot = ks*4 + g;
        short8 af[4];
        #pragma unroll
        for (int mt = 0; mt < 4; ++mt){
            const int row = wr*64 + mt*16 + li;
            af[mt] = *(const short8*)&As[row*128 + ((slot ^ (row & 7)) << 3)];
        }
        #pragma unroll
        for (int nt = 0; nt < 4; ++nt){
            const int e = wc*64 + nt*16 + li;
            const short8 bfv = *(const short8*)&Ws[e*128 + ((slot ^ (e & 7)) << 3)];
            #pragma unroll
            for (int mt = 0; mt < 4; ++mt)
                acc[mt][nt] = MFMA16(af[mt], bfv, acc[mt][nt]);
        }
    }

    #pragma unroll
    for (int mt = 0; mt < 4; ++mt){
        #pragma unroll
        for (int nt = 0; nt < 4; ++nt){
            const int e = wc*64 + nt*16 + li;
            #pragma unroll
            for (int q = 0; q < 4; ++q){
                const size_t pos = (size_t)pbase + wr*64 + mt*16 + g*4 + q;
                float v = acc[mt][nt][q];
                if (MODE == 1) v *= QSCALE;
                else if (MODE == 2) v = 1.f/(1.f + __expf(-(v + bgv[e])));
                if (MODE == 3){
                    ((float*)Outp)[pos*DD + e] = v + bov[e] + xres[pos*DD + e];
                } else {
                    ((u16*)Outp)[pos*DD + e] = f2b(v);
                }
            }
        }
    }
}

// ---------------- MFMA attention: one block per (h, r), 4 waves x 5 Q-tiles ----------------
// Swapped QK^T: St = mfma(K, Q) -> lane (g,li) holds S[i=li][j = jt*16+4g+q].
// Softmax lane-local + shfl_xor(16,32). P->A-frags via cvt_pk + shfl. PV via MFMA.
template<int ROWPASS>
__global__ __launch_bounds__(256) void k_attn_mfma(
    const u16* __restrict__ Pq, const u16* __restrict__ Pk, const u16* __restrict__ Pv,
    const u16* __restrict__ Pg, const float* __restrict__ biasT, u16* __restrict__ Aout)
{
    __shared__ u16 ks[320*32];   // [j][e], slot swizzle: slot ^= j&3
    __shared__ u16 vt[32*320];   // [e][j] transposed, slot swizzle: slot ^= e&7
    const int h = blockIdx.x, r = blockIdx.y;
    const int tid = threadIdx.x;

    #pragma unroll
    for (int c = 0; c < 5; ++c){
        const int flat = tid + c*256;      // 0..1279
        const int j = flat >> 2, s = flat & 3;
        const size_t pos = ROWPASS ? ((size_t)r*NN + j) : ((size_t)j*NN + r);
        const uint4 k4 = *(const uint4*)(Pk + pos*DD + h*DHH + s*8);
        *(uint4*)&ks[j*32 + ((s ^ (j & 3)) << 3)] = k4;
        const uint4 v4 = *(const uint4*)(Pv + pos*DD + h*DHH + s*8);
        union { uint4 q; u16 us[8]; } vu; vu.q = v4;
        #pragma unroll
        for (int u = 0; u < 8; ++u){
            const int e = s*8 + u;
            vt[e*320 + (((j >> 3) ^ (e & 7)) << 3) + (j & 7)] = vu.us[u];
        }
    }
    __syncthreads();

    const int w = tid >> 6, l = tid & 63;
    const int li = l & 15, g = l >> 4;

    for (int t = 0; t < 5; ++t){
        const int i0 = (w + t*4) * 16;
        // Q B-fragment straight from global: lane (g,li) -> Q[i0+li][g*8..+8]
        const int iq = i0 + li;
        const size_t qpos = ROWPASS ? ((size_t)r*NN + iq) : ((size_t)iq*NN + r);
        const short8 qf = *(const short8*)(Pq + qpos*DD + h*DHH + g*8);

        // QK^T: 20 j-tiles
        f32x4 st[20];
        #pragma unroll
        for (int jt = 0; jt < 20; ++jt){
            const int jr = jt*16 + li;
            const short8 kf = *(const short8*)&ks[jr*32 + ((g ^ (jr & 3)) << 3)];
            const f32x4 z = {0.f, 0.f, 0.f, 0.f};
            st[jt] = MFMA16(kf, qf, z);
        }
        // + bias (transposed layout -> coalesced over li)
        const float* bTp = biasT + (size_t)h*NP + i0 + li;
        #pragma unroll
        for (int jt = 0; jt < 20; ++jt){
            const int jb = jt*16 + g*4;
            #pragma unroll
            for (int q = 0; q < 4; ++q)
                st[jt][q] += bTp[(size_t)(jb + q)*NN];
        }
        // softmax over j (lane holds 80 of row li's 320 values)
        float mx = -1e30f;
        #pragma unroll
        for (int jt = 0; jt < 20; ++jt){
            mx = fmaxf(mx, fmaxf(fmaxf(st[jt][0], st[jt][1]), fmaxf(st[jt][2], st[jt][3])));
        }
        mx = fmaxf(mx, __shfl_xor(mx, 16));
        mx = fmaxf(mx, __shfl_xor(mx, 32));
        float sum = 0.f;
        #pragma unroll
        for (int jt = 0; jt < 20; ++jt){
            #pragma unroll
            for (int q = 0; q < 4; ++q){
                const float e = __expf(st[jt][q] - mx);
                st[jt][q] = e; sum += e;
            }
        }
        sum += __shfl_xor(sum, 16);
        sum += __shfl_xor(sum, 32);
        const float inv = 1.f / sum;

        // PV: O[i][e] = sum_j P[i][j] V[j][e]
        f32x4 o0 = {0.f,0.f,0.f,0.f}, o1 = {0.f,0.f,0.f,0.f};
        #pragma unroll
        for (int kt = 0; kt < 10; ++kt){
            // pack this lane's P pairs for tiles 2kt (A) and 2kt+1 (B)
            const u32 Alo = cvtpk(st[2*kt][0],   st[2*kt][1]);
            const u32 Ahi = cvtpk(st[2*kt][2],   st[2*kt][3]);
            const u32 Blo = cvtpk(st[2*kt+1][0], st[2*kt+1][1]);
            const u32 Bhi = cvtpk(st[2*kt+1][2], st[2*kt+1][3]);
            // redistribute: target group g gets j = 32kt + 8g .. +8
            const int s01 = li + ((l & 16) << 1);   // source group 0 or 2 (same li)
            const int s23 = s01 + 16;               // source group 1 or 3
            const u32 a0 = __shfl(Alo, s01), b0 = __shfl(Blo, s01);
            const u32 a1 = __shfl(Ahi, s01), b1 = __shfl(Bhi, s01);
            const u32 a2 = __shfl(Alo, s23), b2 = __shfl(Blo, s23);
            const u32 a3 = __shfl(Ahi, s23), b3 = __shfl(Bhi, s23);
            const bool hi = (l & 32) != 0;          // target groups 2,3 take tile 2kt+1
            union { u32 u[4]; short8 s8; } pu;
            pu.u[0] = hi ? b0 : a0;
            pu.u[1] = hi ? b1 : a1;
            pu.u[2] = hi ? b2 : a2;
            pu.u[3] = hi ? b3 : a3;
            // V B-frags: vt[e][kt*32 + g*8 .. +8], e = et*16 + li
            const int jv = kt*32 + g*8;
            const short8 v0 = *(const short8*)&vt[li*320        + (((jv >> 3) ^ (li & 7)) << 3)];
            const short8 v1 = *(const short8*)&vt[(16+li)*320   + (((jv >> 3) ^ ((16+li) & 7)) << 3)];
            o0 = MFMA16(pu.s8, v0, o0);
            o1 = MFMA16(pu.s8, v1, o1);
        }

        // epilogue: rows i = i0 + 4g + q; col e = et*16 + li
        float invq[4];
        #pragma unroll
        for (int q = 0; q < 4; ++q) invq[q] = __shfl(inv, g*20 + q);
        #pragma unroll
        for (int et = 0; et < 2; ++et){
            const f32x4 oo = et ? o1 : o0;
            #pragma unroll
            for (int q = 0; q < 4; ++q){
                const int i = i0 + g*4 + q;
                const size_t pos = ROWPASS ? ((size_t)r*NN + i) : ((size_t)i*NN + r);
                const size_t off = pos*DD + h*DHH + et*16 + li;
                Aout[off] = f2b(oo[q] * invq[q] * b2f(Pg[off]));
            }
        }
    }
}

// ---------------- host-side launch ----------------
extern "C" void kernel_launch(void* const* d_in, const int* in_sizes, int n_in,
                              void* d_out, int out_size, void* d_ws, size_t ws_size,
                              hipStream_t stream)
{
    const float* x = (const float*)d_in[0];
    float* out = (float*)d_out;
    char* ws = (char*)d_ws;

    u16*   xn    = (u16*)ws;                                  // NP*DD bf16 (aliased as attn out)
    float* biasT = (float*)(ws + (size_t)NP*DD*2);            // NH*NP f32, transposed [h][j][i]
    u16*   Pq    = (u16*)(ws + (size_t)NP*DD*2 + (size_t)NH*NP*4);
    u16*   Pk    = Pq + (size_t)NP*DD;
    u16*   Pv    = Pk + (size_t)NP*DD;
    u16*   Pg    = Pv + (size_t)NP*DD;
    u16*   Aatt  = xn;   // xn is dead after the projection GEMMs

    for (int pass = 0; pass < 2; ++pass){
        void* const* W = d_in + 1 + pass*9;
        const float* ng = (const float*)W[0];
        const float* nb = (const float*)W[1];
        const float* wb = (const float*)W[2];
        const float* wq = (const float*)W[3];
        const float* wkv= (const float*)W[4];
        const float* wg = (const float*)W[5];
        const float* bg = (const float*)W[6];
        const float* wo = (const float*)W[7];
        const float* bo = (const float*)W[8];
        const float* xin = (pass == 0) ? x : out;

        k_ln_bias<<<NP/4, 256, 0, stream>>>(xin, ng, nb, wb, xn, biasT);
        k_gemm_mfma<1><<<NP/128, 256, 0, stream>>>(xn, wq,          (void*)Pq, nullptr, nullptr, nullptr);
        k_gemm_mfma<0><<<NP/128, 256, 0, stream>>>(xn, wkv,         (void*)Pk, nullptr, nullptr, nullptr);
        k_gemm_mfma<0><<<NP/128, 256, 0, stream>>>(xn, wkv + DD*DD, (void*)Pv, nullptr, nullptr, nullptr);
        k_gemm_mfma<2><<<NP/128, 256, 0, stream>>>(xn, wg,          (void*)Pg, bg, nullptr, nullptr);
        if (pass == 0) k_attn_mfma<1><<<dim3(NH, NN), 256, 0, stream>>>(Pq, Pk, Pv, Pg, biasT, Aatt);
        else           k_attn_mfma<0><<<dim3(NH, NN), 256, 0, stream>>>(Pq, Pk, Pv, Pg, biasT, Aatt);
        k_gemm_mfma<3><<<NP/128, 256, 0, stream>>>(Aatt, wo, (void*)out, nullptr, bo, xin);
    }
}